// Round 18
// baseline (81.977 us; speedup 1.0000x reference)
//
#include <hip/hip_runtime.h>
#include <math.h>

#define N_NODES  32
#define N_HEADS  4
#define CDIM     256           // N_HEADS * HEAD_DIM == channels
#define HWPIX    9216          // 96*96
#define ROWF4    2304          // HWPIX/4 float4 per (n,c) row
#define E_BASE   512
#define E_TOT    544           // + 32 self loops
#define NEG_SLOPE 0.2f
#define XS       257           // LDS stride for H tile (conflict-free)
#define HGRID    256           // 1 block/CU -> all co-resident, spin-safe

// ---------------------------------------------------------------------------
// Kernel 1: spatial mean pool — byte-identical to R7 (at BW roofline).
// ---------------------------------------------------------------------------
__global__ __launch_bounds__(256, 4) void pool_kernel(const float* __restrict__ roi,
                                                      float* __restrict__ x) {
    const int wave = threadIdx.x >> 6, lane = threadIdx.x & 63;
    const int row = blockIdx.x * 4 + wave;            // 0..8191  (n*256+c)
    const float4* p = reinterpret_cast<const float4*>(roi) + (size_t)row * ROWF4 + lane;

    float4 A[12], B[12];
    float s = 0.f;

#pragma unroll
    for (int j = 0; j < 12; ++j) A[j] = p[j * 64];              // chunk 0 -> A
#pragma unroll
    for (int j = 0; j < 12; ++j) B[j] = p[(12 + j) * 64];       // chunk 1 -> B
#pragma unroll
    for (int j = 0; j < 12; ++j) s += (A[j].x + A[j].y) + (A[j].z + A[j].w);
#pragma unroll
    for (int j = 0; j < 12; ++j) A[j] = p[(24 + j) * 64];       // chunk 2 -> A
#pragma unroll
    for (int j = 0; j < 12; ++j) s += (B[j].x + B[j].y) + (B[j].z + B[j].w);
#pragma unroll
    for (int j = 0; j < 12; ++j) s += (A[j].x + A[j].y) + (A[j].z + A[j].w);

#pragma unroll
    for (int off = 32; off; off >>= 1) s += __shfl_down(s, off);
    if (lane == 0) x[row] = s * (1.0f / (float)HWPIX);
}

// ---------------------------------------------------------------------------
// Kernel 2: fused H + GAT + classifier with device-scope handshake.
// All 256 blocks: H slice (node b>>3, cols (b&7)*32) — R17's h body.
// Blocks 0..31 pre-issue gat-independent loads (hidden under H), release,
// spin until all 256 slices land, acquire, then run R17's W-free gat body.
// 1 block/CU -> all co-resident (no deadlock). No fragile register pipeline
// to protect (the R9/R10 failure mode was pool-specific).
// ---------------------------------------------------------------------------
__global__ __launch_bounds__(256) void hgat_kernel(const float* __restrict__ x,
                                                   const float* __restrict__ W,
                                                   const int*   __restrict__ edge_index,
                                                   const float* __restrict__ a_src,
                                                   const float* __restrict__ a_dst,
                                                   const float* __restrict__ gat_bias,
                                                   const float* __restrict__ cls_W,
                                                   const float* __restrict__ cls_b,
                                                   float*       __restrict__ H,
                                                   unsigned*    __restrict__ counter,
                                                   float*       __restrict__ out) {
    const int b = blockIdx.x, t = threadIdx.x;
    const bool consumer = (b < N_NODES);

    __shared__ float xrow[CDIM];                      // h phase
    __shared__ float part[8][32];
    __shared__ float    hs[N_NODES * XS];             // gat phase (32,896 B)
    __shared__ __align__(16) float asl[CDIM];
    __shared__ __align__(16) float adl[CDIM];
    __shared__ float    als[N_NODES * N_HEADS];
    __shared__ float    adn[N_HEADS];
    __shared__ unsigned msegu[N_HEADS];
    __shared__ float    M[N_NODES * N_HEADS];
    __shared__ float    sv[CDIM];
    __shared__ float    cred[8][32];

    // ---- consumer pre-issued loads (latency hides under the H phase) ------
    float asr = 0.f, adr = 0.f, gb = 0.f, cb = 0.f;
    int es0 = 0, ed0 = -1, es1 = 0, ed1 = -1;
    float cw[32];
    if (consumer) {
        asr = a_src[t]; adr = a_dst[t]; gb = gat_bias[t];
        es0 = edge_index[t];       ed0 = edge_index[E_BASE + t];
        es1 = edge_index[256 + t]; ed1 = edge_index[E_BASE + 256 + t];
        if (t < 32) cb = cls_b[t];
        const int j = t & 31, g = t >> 5;
#pragma unroll
        for (int i = 0; i < 32; ++i) cw[i] = cls_W[(g * 32 + i) * 32 + j];
    }

    // ======================= H slice (all blocks) ==========================
    {
        const int s = b >> 3, colbase = (b & 7) * 32;
        xrow[t] = x[s * CDIM + t];                    // coalesced 1 KB
        __syncthreads();
        const int j = t & 31, q = t >> 5;
        const float* wp = W + (size_t)(q * 32) * CDIM + colbase + j;
        const float* xq = &xrow[q * 32];
        float acc = 0.f;
#pragma unroll
        for (int i = 0; i < 32; ++i)                  // 32 loads, one batch
            acc += xq[i] * wp[(size_t)i * CDIM];
        part[q][j] = acc;
        __syncthreads();
        if (t < 32) {
            float a = 0.f;
#pragma unroll
            for (int qq = 0; qq < 8; ++qq) a += part[qq][t];
            H[s * CDIM + colbase + t] = a;
        }
    }
    __threadfence();                                  // all threads: release H
    __syncthreads();
    if (t == 0)
        __hip_atomic_fetch_add(counter, 1u, __ATOMIC_RELEASE,
                               __HIP_MEMORY_SCOPE_AGENT);
    if (!consumer) return;                            // producers done

    // ======================= spin until H complete =========================
    if (t == 0) {
        while (__hip_atomic_load(counter, __ATOMIC_RELAXED,
                                 __HIP_MEMORY_SCOPE_AGENT) < HGRID)
            __builtin_amdgcn_s_sleep(2);
        __threadfence();                              // acquire
    }
    __syncthreads();

    // ======================= gat body (R17, W-free) ========================
    const int n = b;

    float4 hv[8];
#pragma unroll
    for (int k = 0; k < 8; ++k) hv[k] = ((const float4*)H)[t + k * 256];

#pragma unroll
    for (int k = 0; k < 8; ++k) {
        const int i = (t + k * 256) * 4, s = i >> 8, c = i & 255;
        hs[s * XS + c + 0] = hv[k].x;
        hs[s * XS + c + 1] = hv[k].y;
        hs[s * XS + c + 2] = hv[k].z;
        hs[s * XS + c + 3] = hv[k].w;
    }
    asl[t] = asr;
    adl[t] = adr;
    if (t < 128) M[t] = 0.f;
    if (t < 4)   msegu[t] = 0u;
    __syncthreads();                                  // B1

    // ---- alphas from H ------------------------------------------------------
    if (t < 132) {
        if (t < 128) {
            const int s = t >> 2, hd = t & 3;
            const float* hrow = &hs[s * XS + hd * 64];
            const float* av   = &asl[hd * 64];
            float acc = 0.f;
#pragma unroll 16
            for (int f = 0; f < 64; ++f) acc += hrow[f] * av[f];
            als[t] = acc;
        } else {
            const int hd = t - 128;
            const float* hrow = &hs[n * XS + hd * 64];
            const float* av   = &adl[hd * 64];
            float acc = 0.f;
#pragma unroll 16
            for (int f = 0; f < 64; ++f) acc += hrow[f] * av[f];
            adn[hd] = acc;
        }
    }
    __syncthreads();                                  // B2

    // ---- pass A: segment max ------------------------------------------------
    {
        const bool sl = (t < 32) && (t == n);
#pragma unroll
        for (int hd = 0; hd < 4; ++hd) {
            float best = -INFINITY;
            if (ed0 == n) {
                float v = als[es0 * 4 + hd] + adn[hd];
                best = fmaxf(best, (v >= 0.f) ? v : NEG_SLOPE * v);
            }
            if (ed1 == n) {
                float v = als[es1 * 4 + hd] + adn[hd];
                best = fmaxf(best, (v >= 0.f) ? v : NEG_SLOPE * v);
            }
            if (sl) {
                float v = als[n * 4 + hd] + adn[hd];
                best = fmaxf(best, (v >= 0.f) ? v : NEG_SLOPE * v);
            }
            if (best > -INFINITY) {
                const int iv = __float_as_int(best);
                const unsigned key = (iv < 0) ? ~(unsigned)iv
                                              : ((unsigned)iv | 0x80000000u);
                atomicMax(&msegu[hd], key);
            }
        }
    }
    __syncthreads();                                  // B3

    float mx[4];
#pragma unroll
    for (int hd = 0; hd < 4; ++hd) {
        const unsigned key = msegu[hd];
        const int im = (key & 0x80000000u) ? (int)(key & 0x7fffffffu) : (int)~key;
        mx[hd] = __int_as_float(im);
    }

    // ---- pass B: exp + unnormalized attention row ---------------------------
    {
        const bool sl = (t < 32) && (t == n);
#pragma unroll
        for (int hd = 0; hd < 4; ++hd) {
            if (ed0 == n) {
                float v = als[es0 * 4 + hd] + adn[hd];
                v = (v >= 0.f) ? v : NEG_SLOPE * v;
                atomicAdd(&M[es0 * 4 + hd], expf(v - mx[hd]));
            }
            if (ed1 == n) {
                float v = als[es1 * 4 + hd] + adn[hd];
                v = (v >= 0.f) ? v : NEG_SLOPE * v;
                atomicAdd(&M[es1 * 4 + hd], expf(v - mx[hd]));
            }
            if (sl) {
                float v = als[n * 4 + hd] + adn[hd];
                v = (v >= 0.f) ? v : NEG_SLOPE * v;
                atomicAdd(&M[n * 4 + hd], expf(v - mx[hd]));
            }
        }
    }
    __syncthreads();                                  // B4

    // ---- aggregation (W-free): out[t] = sum_s M*hs[s][t]/sum_s M + b; SiLU --
    {
        const int hd = t >> 6;
        float acc = 0.f, msum = 0.f;
#pragma unroll
        for (int s = 0; s < N_NODES; ++s) {
            const float m = M[s * 4 + hd];            // wave-uniform broadcast
            msum += m;
            acc += m * hs[s * XS + t];                // 2-way bank alias: free
        }
        const float v = acc / msum + gb;
        sv[t] = v / (1.0f + expf(-v));
    }
    __syncthreads();                                  // B5

    // ---- classifier: cls_W already in registers -----------------------------
    {
        const int j = t & 31, g = t >> 5;
        float a = 0.f;
#pragma unroll
        for (int i = 0; i < 32; ++i) a += sv[g * 32 + i] * cw[i];
        cred[g][j] = a;
    }
    __syncthreads();                                  // B6
    if (t < 32) {
        float s2 = cb;
#pragma unroll
        for (int g = 0; g < 8; ++g) s2 += cred[g][t];
        out[n * 32 + t] = s2;
    }
}

// ---------------------------------------------------------------------------
extern "C" void kernel_launch(void* const* d_in, const int* in_sizes, int n_in,
                              void* d_out, int out_size, void* d_ws, size_t ws_size,
                              hipStream_t stream) {
    const float* roi   = (const float*)d_in[0];
    const int*   eidx  = (const int*)d_in[1];
    const float* W     = (const float*)d_in[2];
    const float* a_src = (const float*)d_in[3];
    const float* a_dst = (const float*)d_in[4];
    const float* gbias = (const float*)d_in[5];
    const float* clsW  = (const float*)d_in[6];
    const float* clsb  = (const float*)d_in[7];
    float* out = (float*)d_out;

    unsigned* counter = (unsigned*)d_ws;               // 64 B
    float*    x       = (float*)((char*)d_ws + 256);   // [8192]
    float*    H       = x + 8192;                      // [8192]

    hipMemsetAsync(d_ws, 0, 64, stream);               // zero counter per replay
    pool_kernel<<<(N_NODES * CDIM) / 4, 256, 0, stream>>>(roi, x);
    hgat_kernel<<<HGRID, 256, 0, stream>>>(x, W, eidx, a_src, a_dst,
                                           gbias, clsW, clsb, H, counter, out);
}

// Round 19
// 59.122 us; speedup vs baseline: 1.3866x; 1.3866x over previous
//
#include <hip/hip_runtime.h>
#include <math.h>

#define N_NODES  32
#define N_HEADS  4
#define CDIM     256           // N_HEADS * HEAD_DIM == channels
#define HWPIX    9216          // 96*96
#define ROWF4    2304          // HWPIX/4 float4 per (n,c) row
#define E_BASE   512
#define E_TOT    544           // + 32 self loops
#define NEG_SLOPE 0.2f
#define XS       257           // LDS stride for H tile (conflict-free)

// ---------------------------------------------------------------------------
// Kernel 1: spatial mean pool — byte-identical to R7 (at BW roofline:
// pool+gap = 44.9 us vs 43.8 ideal, R8 subtraction probe).
// ---------------------------------------------------------------------------
__global__ __launch_bounds__(256, 4) void pool_kernel(const float* __restrict__ roi,
                                                      float* __restrict__ x) {
    const int wave = threadIdx.x >> 6, lane = threadIdx.x & 63;
    const int row = blockIdx.x * 4 + wave;            // 0..8191  (n*256+c)
    const float4* p = reinterpret_cast<const float4*>(roi) + (size_t)row * ROWF4 + lane;

    float4 A[12], B[12];
    float s = 0.f;

#pragma unroll
    for (int j = 0; j < 12; ++j) A[j] = p[j * 64];              // chunk 0 -> A
#pragma unroll
    for (int j = 0; j < 12; ++j) B[j] = p[(12 + j) * 64];       // chunk 1 -> B
#pragma unroll
    for (int j = 0; j < 12; ++j) s += (A[j].x + A[j].y) + (A[j].z + A[j].w);
#pragma unroll
    for (int j = 0; j < 12; ++j) A[j] = p[(24 + j) * 64];       // chunk 2 -> A
#pragma unroll
    for (int j = 0; j < 12; ++j) s += (B[j].x + B[j].y) + (B[j].z + B[j].w);
#pragma unroll
    for (int j = 0; j < 12; ++j) s += (A[j].x + A[j].y) + (A[j].z + A[j].w);

#pragma unroll
    for (int off = 32; off; off >>= 1) s += __shfl_down(s, off);
    if (lane == 0) x[row] = s * (1.0f / (float)HWPIX);
}

// ---------------------------------------------------------------------------
// Kernel 2: H = x @ W  (32x256). 256 blocks: block b -> node s = b>>3,
// col slice [32(b&7), +32). Each block reads a DISJOINT 32 KB W slice —
// W is read once across the whole grid (256 KB total).
// ---------------------------------------------------------------------------
__global__ __launch_bounds__(256) void h_kernel(const float* __restrict__ x,
                                                const float* __restrict__ W,
                                                float* __restrict__ H) {
    const int b = blockIdx.x;
    const int s = b >> 3, colbase = (b & 7) * 32;
    const int t = threadIdx.x;
    __shared__ float xrow[CDIM];
    __shared__ float part[8][32];

    xrow[t] = x[s * CDIM + t];                        // coalesced 1 KB
    __syncthreads();

    const int j = t & 31, q = t >> 5;                 // col j, c-chunk q
    const float* wp = W + (size_t)(q * 32) * CDIM + colbase + j;
    const float* xq = &xrow[q * 32];
    float acc = 0.f;
#pragma unroll
    for (int i = 0; i < 32; ++i)                      // 32 loads, one batch
        acc += xq[i] * wp[(size_t)i * CDIM];
    part[q][j] = acc;
    __syncthreads();

    if (t < 32) {
        float a = 0.f;
#pragma unroll
        for (int qq = 0; qq < 8; ++qq) a += part[qq][t];
        H[s * CDIM + colbase + t] = a;
    }
}

// ---------------------------------------------------------------------------
// Kernel 3: GAT + classifier — W-free (R17, measured 59.2 us total).
// alphas from H; aggregation = sum_s M*H[s] with folded denominator.
// Global traffic: H 32 KB + cls_W 32 KB + ~4 KB, all L2/L3-hot.
// ---------------------------------------------------------------------------
__global__ __launch_bounds__(256) void gat_kernel(const int* __restrict__ edge_index,
                                                  const float* __restrict__ H,
                                                  const float* __restrict__ a_src,
                                                  const float* __restrict__ a_dst,
                                                  const float* __restrict__ gat_bias,
                                                  const float* __restrict__ cls_W,
                                                  const float* __restrict__ cls_b,
                                                  float* __restrict__ out) {
    const int n = blockIdx.x;                         // dst node this block owns
    const int t = threadIdx.x;

    __shared__ float    hs[N_NODES * XS];             // H tile, stride 257
    __shared__ __align__(16) float asl[CDIM];         // a_src flat
    __shared__ __align__(16) float adl[CDIM];         // a_dst flat
    __shared__ float    als[N_NODES * N_HEADS];       // alpha_src, all nodes
    __shared__ float    adn[N_HEADS];                 // alpha_dst, own node
    __shared__ unsigned msegu[N_HEADS];
    __shared__ float    M[N_NODES * N_HEADS];         // attention row [s][hd]
    __shared__ float    sv[CDIM];                     // silu(out_gat)
    __shared__ float    cred[8][32];                  // classifier partials

    // ---- upfront independent global loads (one flight batch) --------------
    float4 hv[8];
#pragma unroll
    for (int k = 0; k < 8; ++k) hv[k] = ((const float4*)H)[t + k * 256];
    const float asr = a_src[t], adr = a_dst[t];
    const float gb = gat_bias[t];
    const int es0 = edge_index[t],       ed0 = edge_index[E_BASE + t];
    const int es1 = edge_index[256 + t], ed1 = edge_index[E_BASE + 256 + t];
    float cb = 0.f;
    if (t < 32) cb = cls_b[t];
    float cw[32];                                     // cls_W[c=32g+i][j=t&31]
    {
        const int j = t & 31, g = t >> 5;
#pragma unroll
        for (int i = 0; i < 32; ++i) cw[i] = cls_W[(g * 32 + i) * 32 + j];
    }

    // ---- LDS staging -------------------------------------------------------
#pragma unroll
    for (int k = 0; k < 8; ++k) {
        const int i = (t + k * 256) * 4, s = i >> 8, c = i & 255;
        hs[s * XS + c + 0] = hv[k].x;
        hs[s * XS + c + 1] = hv[k].y;
        hs[s * XS + c + 2] = hv[k].z;
        hs[s * XS + c + 3] = hv[k].w;
    }
    asl[t] = asr;
    adl[t] = adr;
    if (t < 128) M[t] = 0.f;
    if (t < 4)   msegu[t] = 0u;
    __syncthreads();                                  // B1

    // ---- alphas from H: als[s,hd] = H[s,hd*64:].a_src[hd]; adn likewise ----
    if (t < 132) {
        if (t < 128) {
            const int s = t >> 2, hd = t & 3;
            const float* hrow = &hs[s * XS + hd * 64];
            const float* av   = &asl[hd * 64];
            float acc = 0.f;
#pragma unroll 16
            for (int f = 0; f < 64; ++f) acc += hrow[f] * av[f];
            als[t] = acc;
        } else {
            const int hd = t - 128;
            const float* hrow = &hs[n * XS + hd * 64];
            const float* av   = &adl[hd * 64];
            float acc = 0.f;
#pragma unroll 16
            for (int f = 0; f < 64; ++f) acc += hrow[f] * av[f];
            adn[hd] = acc;
        }
    }
    __syncthreads();                                  // B2

    // ---- pass A: segment max (edges in registers, monotone-uint atomicMax) -
    {
        const bool sl = (t < 32) && (t == n);         // self loop (s0=t,d=t)
#pragma unroll
        for (int hd = 0; hd < 4; ++hd) {
            float best = -INFINITY;
            if (ed0 == n) {
                float v = als[es0 * 4 + hd] + adn[hd];
                best = fmaxf(best, (v >= 0.f) ? v : NEG_SLOPE * v);
            }
            if (ed1 == n) {
                float v = als[es1 * 4 + hd] + adn[hd];
                best = fmaxf(best, (v >= 0.f) ? v : NEG_SLOPE * v);
            }
            if (sl) {
                float v = als[n * 4 + hd] + adn[hd];
                best = fmaxf(best, (v >= 0.f) ? v : NEG_SLOPE * v);
            }
            if (best > -INFINITY) {
                const int iv = __float_as_int(best);
                const unsigned key = (iv < 0) ? ~(unsigned)iv
                                              : ((unsigned)iv | 0x80000000u);
                atomicMax(&msegu[hd], key);
            }
        }
    }
    __syncthreads();                                  // B3

    float mx[4];
#pragma unroll
    for (int hd = 0; hd < 4; ++hd) {
        const unsigned key = msegu[hd];
        const int im = (key & 0x80000000u) ? (int)(key & 0x7fffffffu) : (int)~key;
        mx[hd] = __int_as_float(im);
    }

    // ---- pass B: exp + unnormalized attention row (denom folded later) -----
    {
        const bool sl = (t < 32) && (t == n);
#pragma unroll
        for (int hd = 0; hd < 4; ++hd) {
            if (ed0 == n) {
                float v = als[es0 * 4 + hd] + adn[hd];
                v = (v >= 0.f) ? v : NEG_SLOPE * v;
                atomicAdd(&M[es0 * 4 + hd], expf(v - mx[hd]));
            }
            if (ed1 == n) {
                float v = als[es1 * 4 + hd] + adn[hd];
                v = (v >= 0.f) ? v : NEG_SLOPE * v;
                atomicAdd(&M[es1 * 4 + hd], expf(v - mx[hd]));
            }
            if (sl) {
                float v = als[n * 4 + hd] + adn[hd];
                v = (v >= 0.f) ? v : NEG_SLOPE * v;
                atomicAdd(&M[n * 4 + hd], expf(v - mx[hd]));
            }
        }
    }
    __syncthreads();                                  // B4

    // ---- aggregation (W-free): out[t] = sum_s M*hs[s][t]/sum_s M + b; SiLU -
    {
        const int hd = t >> 6;
        float acc = 0.f, msum = 0.f;
#pragma unroll
        for (int s = 0; s < N_NODES; ++s) {
            const float m = M[s * 4 + hd];            // wave-uniform broadcast
            msum += m;
            acc += m * hs[s * XS + t];                // 2-way bank alias: free
        }
        const float v = acc / msum + gb;
        sv[t] = v / (1.0f + expf(-v));
    }
    __syncthreads();                                  // B5

    // ---- classifier: 8 groups x 32 cols, cls_W already in registers --------
    {
        const int j = t & 31, g = t >> 5;
        float a = 0.f;
#pragma unroll
        for (int i = 0; i < 32; ++i) a += sv[g * 32 + i] * cw[i];
        cred[g][j] = a;
    }
    __syncthreads();                                  // B6
    if (t < 32) {
        float s2 = cb;
#pragma unroll
        for (int g = 0; g < 8; ++g) s2 += cred[g][t];
        out[n * 32 + t] = s2;
    }
}

// ---------------------------------------------------------------------------
extern "C" void kernel_launch(void* const* d_in, const int* in_sizes, int n_in,
                              void* d_out, int out_size, void* d_ws, size_t ws_size,
                              hipStream_t stream) {
    const float* roi   = (const float*)d_in[0];
    const int*   eidx  = (const int*)d_in[1];
    const float* W     = (const float*)d_in[2];
    const float* a_src = (const float*)d_in[3];
    const float* a_dst = (const float*)d_in[4];
    const float* gbias = (const float*)d_in[5];
    const float* clsW  = (const float*)d_in[6];
    const float* clsb  = (const float*)d_in[7];
    float* out = (float*)d_out;

    float* x = (float*)d_ws;                   // [8192] floats
    float* H = x + 8192;                       // [8192] floats

    pool_kernel<<<(N_NODES * CDIM) / 4, 256, 0, stream>>>(roi, x);
    h_kernel<<<256, 256, 0, stream>>>(x, W, H);
    gat_kernel<<<N_NODES, 256, 0, stream>>>(eidx, H, a_src, a_dst,
                                            gbias, clsW, clsb, out);
}